// Round 4
// baseline (3412.977 us; speedup 1.0000x reference)
//
#include <hip/hip_runtime.h>
#include <cstdint>
#include <cstddef>

// Problem constants (reference: T,B,H_IN,H_HID = 2048,64,256,256)
#define T_LEN 2048
#define B_N   64
#define H_INP 256
#define H_HID 256
#define G3    768              // 3*H_HID (gates r,z,n)
#define M_ROWS (T_LEN * B_N)   // 131072
#define SCH   8                // scan steps per LDS chunk

typedef _Float16 f16;
typedef _Float16 f16x2 __attribute__((ext_vector_type(2)));
typedef _Float16 f16x8 __attribute__((ext_vector_type(8)));
typedef float    f32x4 __attribute__((ext_vector_type(4)));

static __device__ __forceinline__ float fdot2f(uint32_t a, uint32_t b, float c) {
#if __has_builtin(__builtin_amdgcn_fdot2)
  return __builtin_amdgcn_fdot2(__builtin_bit_cast(f16x2, a),
                                __builtin_bit_cast(f16x2, b), c, false);
#else
  f16x2 av = __builtin_bit_cast(f16x2, a);
  f16x2 bv = __builtin_bit_cast(f16x2, b);
  return c + (float)av.x * (float)bv.x + (float)av.y * (float)bv.y;
#endif
}

// ---------------------------------------------------------------- zero d_out
__global__ void k_zero(float4* __restrict__ p, int n4) {
  int i = blockIdx.x * blockDim.x + threadIdx.x;
  int stride = gridDim.x * blockDim.x;
  float4 z; z.x = z.y = z.z = z.w = 0.f;
  for (; i < n4; i += stride) p[i] = z;
}

// ------------------------------------------------------------- f32 -> f16
__global__ void k_cvt(const float2* __restrict__ s, f16x2* __restrict__ d, int n2) {
  int i = blockIdx.x * blockDim.x + threadIdx.x;
  int stride = gridDim.x * blockDim.x;
  for (; i < n2; i += stride) {
    float2 v = s[i];
    f16x2 p; p.x = (f16)v.x; p.y = (f16)v.y;
    d[i] = p;
  }
}

// ---------------------------------------------- per-column pack: tidx, lens
__global__ __launch_bounds__(64) void k_prep_col(const int* __restrict__ mask,
                                                 unsigned short* __restrict__ tidx,
                                                 int* __restrict__ lens) {
  const int b = blockIdx.x;
  const int lane = threadIdx.x;
  unsigned short* tp = tidx + b * T_LEN;
  int base = 0;
  for (int c = 0; c < T_LEN / 64; ++c) {
    int t = c * 64 + lane;
    bool m = mask[t * B_N + b] != 0;
    unsigned long long bal = __ballot(m);
    int pc = __popcll(bal & ((1ull << lane) - 1ull));
    if (m) tp[base + pc] = (unsigned short)t;
    base += __popcll(bal);
  }
  if (lane == 0) lens[b] = base;
}

// --------------------------------------------------- per-row true counts
__global__ __launch_bounds__(256) void k_rowcnt(const int* __restrict__ mask,
                                                int* __restrict__ rowcnt) {
  int g = blockIdx.x * 256 + threadIdx.x;
  int t = g >> 6, lane = g & 63;
  bool m = mask[t * B_N + lane] != 0;
  unsigned long long bal = __ballot(m);
  if (lane == 0) rowcnt[t] = __popcll(bal);
}

// ------------------------------------------- exclusive prefix of rowcnt[2048]
__global__ __launch_bounds__(512) void k_rowpref(const int* __restrict__ rowcnt,
                                                 int* __restrict__ rowpref,
                                                 int* __restrict__ ntru) {
  const int tid = threadIdx.x;
  const int lane = tid & 63, w = tid >> 6;
  int4 v = ((const int4*)rowcnt)[tid];
  int s = v.x + v.y + v.z + v.w;
  int incl = s;
  for (int d = 1; d < 64; d <<= 1) {
    int t = __shfl_up(incl, d, 64);
    if (lane >= d) incl += t;
  }
  __shared__ int wt[8], wo[8];
  if (lane == 63) wt[w] = incl;
  __syncthreads();
  if (tid == 0) {
    int run = 0;
    for (int i = 0; i < 8; ++i) { wo[i] = run; run += wt[i]; }
    ntru[0] = run;
  }
  __syncthreads();
  int base = wo[w] + incl - s;
  int4 o; o.x = base; o.y = base + v.x; o.z = o.y + v.y; o.w = o.z + v.z;
  ((int4*)rowpref)[tid] = o;
}

// --------------------------------------------------- inverse permutation
__global__ __launch_bounds__(256) void k_inv(const int* __restrict__ mask,
                                             const int* __restrict__ rowpref,
                                             int* __restrict__ inv) {
  int g = blockIdx.x * 256 + threadIdx.x;
  int t = g >> 6, lane = g & 63;
  bool m = mask[t * B_N + lane] != 0;
  unsigned long long bal = __ballot(m);
  int r = rowpref[t] + __popcll(bal & ((1ull << lane) - 1ull));
  if (m) inv[r] = t * B_N + lane;
}

// ---------------------------- invT[b][k] = (k*64+b < Nt) ? inv[k*64+b] : -1
__global__ __launch_bounds__(256) void k_invT(const int* __restrict__ inv,
                                              const int* __restrict__ ntru,
                                              int* __restrict__ invT) {
  int j = blockIdx.x * 256 + threadIdx.x;   // j = k*B + b
  int v = (j < ntru[0]) ? inv[j] : -1;
  invT[(j & 63) * T_LEN + (j >> 6)] = v;
}

// ------------------------------------------- gi = X @ W_ih^T + b_ih (f16 MFMA)
__global__ __launch_bounds__(256) void k_gemm(const f16* __restrict__ X,
                                              const f16* __restrict__ W,
                                              const float* __restrict__ bias,
                                              f16* __restrict__ GI) {
  const int lane = threadIdx.x & 63;
  const int wave = threadIdx.x >> 6;
  const int m0 = blockIdx.x * 64 + wave * 16;
  const int n0 = blockIdx.y * 64;
  const int idx16 = lane & 15;
  const int kofs  = (lane >> 4) * 8;

  const f16* ap  = X + (size_t)(m0 + idx16) * H_INP + kofs;
  const f16* bp0 = W + (size_t)(n0 + idx16) * H_INP + kofs;

  f32x4 acc[4] = { {0,0,0,0}, {0,0,0,0}, {0,0,0,0}, {0,0,0,0} };
#pragma unroll
  for (int kt = 0; kt < 8; ++kt) {
    f16x8 a = *(const f16x8*)(ap + kt * 32);
#pragma unroll
    for (int nt = 0; nt < 4; ++nt) {
      f16x8 bb = *(const f16x8*)(bp0 + (size_t)nt * 16 * H_INP + kt * 32);
      acc[nt] = __builtin_amdgcn_mfma_f32_16x16x32_f16(a, bb, acc[nt], 0, 0, 0);
    }
  }
  const int mbase = m0 + (lane >> 4) * 4;
#pragma unroll
  for (int nt = 0; nt < 4; ++nt) {
    const int col = n0 + nt * 16 + idx16;
    const float bv = bias[col];
#pragma unroll
    for (int r = 0; r < 4; ++r)
      GI[(size_t)(mbase + r) * G3 + col] = (f16)(acc[nt][r] + bv);
  }
}

// -------------------------------------------------- GRU scan, 1 column / block
// 768 threads = 12 waves. k-chunked weight ownership: thread t owns chunk
// c = t&7 (32 of 256 h-elements) of rows 8*(t>>3)..+7 -> 128 w dwords in
// VGPRs, but only 64 B of h broadcast per thread per step (4 ds_read_b128
// from a stride-20-dword padded h layout: all 8 chunk addresses hit disjoint
// 4-bank groups -> conflict-free). Octet shfl_xor butterfly (static reg
// indices via cndmask) reduces the 8 partials so thread t ends with gh[row t].
// GI prefetched with distance-1 chunk pipelining; tidx/inv staged in LDS once.
__global__ __launch_bounds__(768, 3) void k_scan(const f16* __restrict__ Whh,
                                                 const f16* __restrict__ GI,
                                                 const float* __restrict__ h0,
                                                 const float* __restrict__ bhh,
                                                 const unsigned short* __restrict__ tidx,
                                                 const int* __restrict__ lens,
                                                 const int* __restrict__ invT,
                                                 float* __restrict__ out) {
  const int b = blockIdx.x;
  const int tid = threadIdx.x;
  const int o = tid & 7;            // k-chunk index
  const int rbase = (tid >> 3) << 3;  // rows rbase..rbase+7

  __shared__ f16      GIbuf[2][SCH * G3];   // 24576 B
  __shared__ float    outb[SCH * H_HID];    //  8192 B
  __shared__ float    ghs[2 * H_HID];       //  2048 B (rows 256..767)
  __shared__ uint32_t hpad[160];            //   640 B (8 chunks, stride 20 dw)
  __shared__ unsigned short tcol[T_LEN];    //  4096 B
  __shared__ int      invcol[T_LEN];        //  8192 B

  const int L = lens[b];

  // ---- weights: rows rbase+i, elements [32*o, 32*o+32) as 4 uint4 each ----
  uint4 wq[8][4];
#pragma unroll
  for (int i = 0; i < 8; ++i) {
    const uint4* wp = (const uint4*)(Whh + (size_t)(rbase + i) * H_HID + 32 * o);
#pragma unroll
    for (int q = 0; q < 4; ++q) wq[i][q] = wp[q];
  }
  const float bias = bhh[tid];

  // ---- stage per-column metadata in LDS ----
  for (int i = tid; i < T_LEN; i += 768) {
    tcol[i] = tidx[b * T_LEN + i];
    invcol[i] = invT[b * T_LEN + i];
  }
  float h_reg = 0.f;
  if (tid < H_HID) {
    h_reg = h0[b * H_HID + tid];
    ((f16*)hpad)[40 * (tid >> 5) + (tid & 31)] = (f16)h_reg;
  }

  // ---- GI prefetch slot mapping: thread = one 16B slot of the 12 KB chunk --
  const int r_s = tid / 96;            // row within chunk (8 rows x 96 slots)
  const int o_s = (tid % 96) * 16;     // byte offset within row
  const char* GIc = (const char*)GI;
  uint4 pref = {0, 0, 0, 0};

  __syncthreads();   // tcol/invcol/hpad ready (needed before first prefetch)

  if (r_s < L) {     // prefetch chunk 0
    int t = tcol[r_s];
    pref = *(const uint4*)(GIc + ((size_t)t * B_N + b) * (G3 * 2) + o_s);
  }

  const int nchunks = (L + SCH - 1) >> 3;
  for (int n = 0; n < nchunks; ++n) {
    const int par = n & 1;
    // deposit prefetched chunk n (loaded one boundary ago; vmcnt long clear)
    if (n * SCH + r_s < L)
      *(uint4*)((char*)GIbuf[par] + tid * 16) = pref;
    // issue prefetch for chunk n+1
    {
      int kk = (n + 1) * SCH + r_s;
      if (kk < L) {
        int t = tcol[kk];
        pref = *(const uint4*)(GIc + ((size_t)t * B_N + b) * (G3 * 2) + o_s);
      }
    }
    // flush chunk n-1 output rows (reads outb before this chunk's gates rewrite)
    if (n > 0 && tid < 512) {
      int r = tid >> 6, c4 = (tid & 63) << 2;
      int kk = (n - 1) * SCH + r;
      if (kk < L) {
        int iv = invcol[kk];
        if (iv >= 0)
          *(float4*)(out + (size_t)iv * H_HID + c4) = *(const float4*)(outb + r * H_HID + c4);
      }
    }

    const int smax = (L - n * SCH < SCH) ? (L - n * SCH) : SCH;
    for (int s = 0; s < smax; ++s) {
      // --- matvec partials: 8 rows x own k-chunk ---
      float a0 = 0.f, a1 = 0.f, a2 = 0.f, a3 = 0.f;
      float a4 = 0.f, a5 = 0.f, a6 = 0.f, a7 = 0.f;
#pragma unroll
      for (int q = 0; q < 4; ++q) {
        uint4 hv = *(const uint4*)(hpad + 20 * o + 4 * q);
        a0 = fdot2f(wq[0][q].x, hv.x, a0); a0 = fdot2f(wq[0][q].y, hv.y, a0);
        a0 = fdot2f(wq[0][q].z, hv.z, a0); a0 = fdot2f(wq[0][q].w, hv.w, a0);
        a1 = fdot2f(wq[1][q].x, hv.x, a1); a1 = fdot2f(wq[1][q].y, hv.y, a1);
        a1 = fdot2f(wq[1][q].z, hv.z, a1); a1 = fdot2f(wq[1][q].w, hv.w, a1);
        a2 = fdot2f(wq[2][q].x, hv.x, a2); a2 = fdot2f(wq[2][q].y, hv.y, a2);
        a2 = fdot2f(wq[2][q].z, hv.z, a2); a2 = fdot2f(wq[2][q].w, hv.w, a2);
        a3 = fdot2f(wq[3][q].x, hv.x, a3); a3 = fdot2f(wq[3][q].y, hv.y, a3);
        a3 = fdot2f(wq[3][q].z, hv.z, a3); a3 = fdot2f(wq[3][q].w, hv.w, a3);
        a4 = fdot2f(wq[4][q].x, hv.x, a4); a4 = fdot2f(wq[4][q].y, hv.y, a4);
        a4 = fdot2f(wq[4][q].z, hv.z, a4); a4 = fdot2f(wq[4][q].w, hv.w, a4);
        a5 = fdot2f(wq[5][q].x, hv.x, a5); a5 = fdot2f(wq[5][q].y, hv.y, a5);
        a5 = fdot2f(wq[5][q].z, hv.z, a5); a5 = fdot2f(wq[5][q].w, hv.w, a5);
        a6 = fdot2f(wq[6][q].x, hv.x, a6); a6 = fdot2f(wq[6][q].y, hv.y, a6);
        a6 = fdot2f(wq[6][q].z, hv.z, a6); a6 = fdot2f(wq[6][q].w, hv.w, a6);
        a7 = fdot2f(wq[7][q].x, hv.x, a7); a7 = fdot2f(wq[7][q].y, hv.y, a7);
        a7 = fdot2f(wq[7][q].z, hv.z, a7); a7 = fdot2f(wq[7][q].w, hv.w, a7);
      }
      // --- octet butterfly: thread t ends with gh[row t] ---
      const bool h4 = (tid & 4), h2 = (tid & 2), h1 = (tid & 1);
      float se, ns, b0, b1, b2, b3, c0, c1;
      se = h4 ? a4 : a0; ns = h4 ? a0 : a4; b0 = se + __shfl_xor(ns, 4);
      se = h4 ? a5 : a1; ns = h4 ? a1 : a5; b1 = se + __shfl_xor(ns, 4);
      se = h4 ? a6 : a2; ns = h4 ? a2 : a6; b2 = se + __shfl_xor(ns, 4);
      se = h4 ? a7 : a3; ns = h4 ? a3 : a7; b3 = se + __shfl_xor(ns, 4);
      se = h2 ? b2 : b0; ns = h2 ? b0 : b2; c0 = se + __shfl_xor(ns, 2);
      se = h2 ? b3 : b1; ns = h2 ? b1 : b3; c1 = se + __shfl_xor(ns, 2);
      se = h1 ? c1 : c0; ns = h1 ? c0 : c1;
      const float gh = se + __shfl_xor(ns, 1) + bias;
      if (tid >= H_HID) ghs[tid - H_HID] = gh;
      __syncthreads();
      // --- gates (threads 0..255; r-row gh is local) ---
      if (tid < H_HID) {
        const f16* gib = GIbuf[par] + s * G3;
        const float gi0 = (float)gib[tid];
        const float gi1 = (float)gib[H_HID + tid];
        const float gi2 = (float)gib[2 * H_HID + tid];
        const float ghz = ghs[tid];
        const float ghn = ghs[H_HID + tid];
        const float rg = __builtin_amdgcn_rcpf(1.f + __expf(-(gi0 + gh)));
        const float zg = __builtin_amdgcn_rcpf(1.f + __expf(-(gi1 + ghz)));
        const float xx = gi2 + rg * ghn;
        const float ng = 1.f - 2.f * __builtin_amdgcn_rcpf(1.f + __expf(2.f * xx));
        const float hn = (1.f - zg) * ng + zg * h_reg;
        h_reg = hn;
        ((f16*)hpad)[40 * (tid >> 5) + (tid & 31)] = (f16)hn;
        outb[s * H_HID + tid] = hn;
      }
      __syncthreads();
    }
  }
  // tail flush (last chunk)
  if (L > 0 && tid < 512) {
    const int nc = nchunks - 1;
    int r = tid >> 6, c4 = (tid & 63) << 2;
    int kk = nc * SCH + r;
    if (kk < L) {
      int iv = invcol[kk];
      if (iv >= 0)
        *(float4*)(out + (size_t)iv * H_HID + c4) = *(const float4*)(outb + r * H_HID + c4);
    }
  }
  if (tid < H_HID)
    out[(size_t)M_ROWS * H_HID + (size_t)b * H_HID + tid] = h_reg;
}

// ---------------------------------------------------------------------------
extern "C" void kernel_launch(void* const* d_in, const int* in_sizes, int n_in,
                              void* d_out, int out_size, void* d_ws, size_t ws_size,
                              hipStream_t stream) {
  const float* x    = (const float*)d_in[0];
  const float* h0   = (const float*)d_in[1];
  const int*   mask = (const int*)d_in[2];
  const float* wih  = (const float*)d_in[3];
  const float* whh  = (const float*)d_in[4];
  const float* bih  = (const float*)d_in[5];
  const float* bhh  = (const float*)d_in[6];
  float* out = (float*)d_out;

  // workspace layout (~270.3 MB; invT reuses the X16 region after k_gemm)
  char* ws = (char*)d_ws;
  f16* X16   = (f16*)(ws + 0);                       //  67,108,864 B
  int* invT  = (int*)(ws + 0);                       //     524,288 B (after gemm)
  f16* Wih16 = (f16*)(ws + 67108864);                //     393,216 B
  f16* Whh16 = (f16*)(ws + 67502080);                //     393,216 B
  f16* GI    = (f16*)(ws + 67895296);                // 201,326,592 B
  unsigned short* tidx = (unsigned short*)(ws + 269221888);  // 262,144 B
  int* rowcnt  = (int*)(ws + 269484032);             //       8,192 B
  int* rowpref = (int*)(ws + 269492224);             //       8,192 B
  int* inv   = (int*)(ws + 269746176);               //     524,288 B
  int* lens  = (int*)(ws + 270270464);               //         256 B
  int* ntru  = (int*)(ws + 270270720);               //           4 B

  hipLaunchKernelGGL(k_zero, dim3(4096), dim3(256), 0, stream,
                     (float4*)d_out, out_size / 4);
  hipLaunchKernelGGL(k_cvt, dim3(4096), dim3(256), 0, stream,
                     (const float2*)x, (f16x2*)X16, M_ROWS * H_INP / 2);
  hipLaunchKernelGGL(k_cvt, dim3(96), dim3(256), 0, stream,
                     (const float2*)wih, (f16x2*)Wih16, G3 * H_INP / 2);
  hipLaunchKernelGGL(k_cvt, dim3(96), dim3(256), 0, stream,
                     (const float2*)whh, (f16x2*)Whh16, G3 * H_INP / 2);
  hipLaunchKernelGGL(k_prep_col, dim3(B_N), dim3(64), 0, stream,
                     mask, tidx, lens);
  hipLaunchKernelGGL(k_rowcnt, dim3(512), dim3(256), 0, stream, mask, rowcnt);
  hipLaunchKernelGGL(k_rowpref, dim3(1), dim3(512), 0, stream,
                     rowcnt, rowpref, ntru);
  hipLaunchKernelGGL(k_inv, dim3(512), dim3(256), 0, stream,
                     mask, rowpref, inv);
  hipLaunchKernelGGL(k_gemm, dim3(M_ROWS / 64, G3 / 64), dim3(256), 0, stream,
                     X16, Wih16, bih, GI);
  hipLaunchKernelGGL(k_invT, dim3(512), dim3(256), 0, stream,
                     inv, ntru, invT);
  hipLaunchKernelGGL(k_scan, dim3(B_N), dim3(768), 0, stream,
                     Whh16, GI, h0, bhh, tidx, lens, invT, out);
}

// Round 5
// 3147.371 us; speedup vs baseline: 1.0844x; 1.0844x over previous
//
#include <hip/hip_runtime.h>
#include <cstdint>
#include <cstddef>

// Problem constants (reference: T,B,H_IN,H_HID = 2048,64,256,256)
#define T_LEN 2048
#define B_N   64
#define H_INP 256
#define H_HID 256
#define G3    768              // 3*H_HID (gates r,z,n)
#define M_ROWS (T_LEN * B_N)   // 131072
#define SCH   8                // scan steps per LDS chunk

typedef _Float16 f16;
typedef _Float16 f16x2 __attribute__((ext_vector_type(2)));
typedef _Float16 f16x8 __attribute__((ext_vector_type(8)));
typedef float    f32x4 __attribute__((ext_vector_type(4)));

static __device__ __forceinline__ float fdot2f(uint32_t a, uint32_t b, float c) {
#if __has_builtin(__builtin_amdgcn_fdot2)
  return __builtin_amdgcn_fdot2(__builtin_bit_cast(f16x2, a),
                                __builtin_bit_cast(f16x2, b), c, false);
#else
  f16x2 av = __builtin_bit_cast(f16x2, a);
  f16x2 bv = __builtin_bit_cast(f16x2, b);
  return c + (float)av.x * (float)bv.x + (float)av.y * (float)bv.y;
#endif
}

// ---- DPP cross-lane helpers (VALU pipe; no LDS traffic) ----
template <int CTRL>
static __device__ __forceinline__ float dppf(float v) {
  return __builtin_bit_cast(float,
      __builtin_amdgcn_update_dpp(0, __builtin_bit_cast(int, v), CTRL, 0xf, 0xf, true));
}
// value from lane^4 (within row-16): row_shl:4 / row_shr:4 selected by bit2
static __device__ __forceinline__ float x4sel(float v, bool hi4) {
  float lo = dppf<0x104>(v);   // dst[l] = src[l+4]
  float hi = dppf<0x114>(v);   // dst[l] = src[l-4]
  return hi4 ? hi : lo;
}
static __device__ __forceinline__ float mrg4(float lo, float hi, bool h) {
  float mine = h ? hi : lo;
  float th   = h ? lo : hi;
  return mine + x4sel(th, h);
}
static __device__ __forceinline__ float mrg2(float lo, float hi, bool h) {
  float mine = h ? hi : lo;
  float th   = h ? lo : hi;
  return mine + dppf<0x4E>(th);   // quad_perm [2,3,0,1] = lane^2
}
static __device__ __forceinline__ float mrg1(float lo, float hi, bool h) {
  float mine = h ? hi : lo;
  float th   = h ? lo : hi;
  return mine + dppf<0xB1>(th);   // quad_perm [1,0,3,2] = lane^1
}

// ---- async global->LDS, 16 B per lane; ldsbase must be wave-uniform ----
static __device__ __forceinline__ void gldl16(const void* g, void* ldsbase, void* ldsexact) {
#if __has_builtin(__builtin_amdgcn_global_load_lds)
  __builtin_amdgcn_global_load_lds((const __attribute__((address_space(1))) void*)g,
                                   (__attribute__((address_space(3))) void*)ldsbase, 16, 0, 0);
  (void)ldsexact;
#else
  *(uint4*)ldsexact = *(const uint4*)g;
#endif
}

// ---------------------------------------------------------------- zero d_out
__global__ void k_zero(float4* __restrict__ p, int n4) {
  int i = blockIdx.x * blockDim.x + threadIdx.x;
  int stride = gridDim.x * blockDim.x;
  float4 z; z.x = z.y = z.z = z.w = 0.f;
  for (; i < n4; i += stride) p[i] = z;
}

// ------------------------------------------------------------- f32 -> f16
__global__ void k_cvt(const float2* __restrict__ s, f16x2* __restrict__ d, int n2) {
  int i = blockIdx.x * blockDim.x + threadIdx.x;
  int stride = gridDim.x * blockDim.x;
  for (; i < n2; i += stride) {
    float2 v = s[i];
    f16x2 p; p.x = (f16)v.x; p.y = (f16)v.y;
    d[i] = p;
  }
}

// ---------------------------------------------- per-column pack: tidx, lens
__global__ __launch_bounds__(64) void k_prep_col(const int* __restrict__ mask,
                                                 unsigned short* __restrict__ tidx,
                                                 int* __restrict__ lens) {
  const int b = blockIdx.x;
  const int lane = threadIdx.x;
  unsigned short* tp = tidx + b * T_LEN;
  int base = 0;
  for (int c = 0; c < T_LEN / 64; ++c) {
    int t = c * 64 + lane;
    bool m = mask[t * B_N + b] != 0;
    unsigned long long bal = __ballot(m);
    int pc = __popcll(bal & ((1ull << lane) - 1ull));
    if (m) tp[base + pc] = (unsigned short)t;
    base += __popcll(bal);
  }
  if (lane == 0) lens[b] = base;
}

// --------------------------------------------------- per-row true counts
__global__ __launch_bounds__(256) void k_rowcnt(const int* __restrict__ mask,
                                                int* __restrict__ rowcnt) {
  int g = blockIdx.x * 256 + threadIdx.x;
  int t = g >> 6, lane = g & 63;
  bool m = mask[t * B_N + lane] != 0;
  unsigned long long bal = __ballot(m);
  if (lane == 0) rowcnt[t] = __popcll(bal);
}

// ------------------------------------------- exclusive prefix of rowcnt[2048]
__global__ __launch_bounds__(512) void k_rowpref(const int* __restrict__ rowcnt,
                                                 int* __restrict__ rowpref,
                                                 int* __restrict__ ntru) {
  const int tid = threadIdx.x;
  const int lane = tid & 63, w = tid >> 6;
  int4 v = ((const int4*)rowcnt)[tid];
  int s = v.x + v.y + v.z + v.w;
  int incl = s;
  for (int d = 1; d < 64; d <<= 1) {
    int t = __shfl_up(incl, d, 64);
    if (lane >= d) incl += t;
  }
  __shared__ int wt[8], wo[8];
  if (lane == 63) wt[w] = incl;
  __syncthreads();
  if (tid == 0) {
    int run = 0;
    for (int i = 0; i < 8; ++i) { wo[i] = run; run += wt[i]; }
    ntru[0] = run;
  }
  __syncthreads();
  int base = wo[w] + incl - s;
  int4 o; o.x = base; o.y = base + v.x; o.z = o.y + v.y; o.w = o.z + v.z;
  ((int4*)rowpref)[tid] = o;
}

// --------------------------------------------------- inverse permutation
__global__ __launch_bounds__(256) void k_inv(const int* __restrict__ mask,
                                             const int* __restrict__ rowpref,
                                             int* __restrict__ inv) {
  int g = blockIdx.x * 256 + threadIdx.x;
  int t = g >> 6, lane = g & 63;
  bool m = mask[t * B_N + lane] != 0;
  unsigned long long bal = __ballot(m);
  int r = rowpref[t] + __popcll(bal & ((1ull << lane) - 1ull));
  if (m) inv[r] = t * B_N + lane;
}

// ---------------------------- invT[b][k] = (k*64+b < Nt) ? inv[k*64+b] : -1
__global__ __launch_bounds__(256) void k_invT(const int* __restrict__ inv,
                                              const int* __restrict__ ntru,
                                              int* __restrict__ invT) {
  int j = blockIdx.x * 256 + threadIdx.x;   // j = k*B + b
  int v = (j < ntru[0]) ? inv[j] : -1;
  invT[(j & 63) * T_LEN + (j >> 6)] = v;
}

// ------------------------------------------- gi = X @ W_ih^T + b_ih (f16 MFMA)
// Epilogue stages each wave's 16x64 C-tile in LDS (pad 72) and stores
// 128 B-contiguous row chunks -> coalesced 201 MB write (was 2 B scatter).
__global__ __launch_bounds__(256) void k_gemm(const f16* __restrict__ X,
                                              const f16* __restrict__ W,
                                              const float* __restrict__ bias,
                                              f16* __restrict__ GI) {
  const int lane = threadIdx.x & 63;
  const int wave = threadIdx.x >> 6;
  const int m0 = blockIdx.x * 64 + wave * 16;
  const int n0 = blockIdx.y * 64;
  const int idx16 = lane & 15;
  const int kofs  = (lane >> 4) * 8;

  __shared__ __align__(16) f16 st[4][16][72];

  const f16* ap  = X + (size_t)(m0 + idx16) * H_INP + kofs;
  const f16* bp0 = W + (size_t)(n0 + idx16) * H_INP + kofs;

  f32x4 acc[4] = { {0,0,0,0}, {0,0,0,0}, {0,0,0,0}, {0,0,0,0} };
#pragma unroll
  for (int kt = 0; kt < 8; ++kt) {
    f16x8 a = *(const f16x8*)(ap + kt * 32);
#pragma unroll
    for (int nt = 0; nt < 4; ++nt) {
      f16x8 bb = *(const f16x8*)(bp0 + (size_t)nt * 16 * H_INP + kt * 32);
      acc[nt] = __builtin_amdgcn_mfma_f32_16x16x32_f16(a, bb, acc[nt], 0, 0, 0);
    }
  }
  // C/D layout: row = (lane>>4)*4 + r, col = lane&15
#pragma unroll
  for (int nt = 0; nt < 4; ++nt) {
    const int col = nt * 16 + idx16;
    const float bv = bias[n0 + col];
#pragma unroll
    for (int r = 0; r < 4; ++r)
      st[wave][(lane >> 4) * 4 + r][col] = (f16)(acc[nt][r] + bv);
  }
  // same-wave LDS RAW (compiler inserts lgkmcnt wait); no barrier needed
  {
    const int row = lane >> 2, seg = lane & 3;
    const uint4* sp = (const uint4*)&st[wave][row][seg * 16];
    uint4 v0 = sp[0], v1 = sp[1];
    uint4* gp = (uint4*)(GI + (size_t)(m0 + row) * G3 + n0 + seg * 16);
    gp[0] = v0; gp[1] = v1;
  }
}

// -------------------------------------------------- GRU scan, 1 column / block
// 512 threads = 8 waves, amdgpu_waves_per_eu(2,2) -> 256-VGPR budget so the
// 192 weight dwords/thread stay in arch VGPRs (84-VGPR default budget was
// spilling them to scratch -> ~3000 cyc/step of L2 reloads in rounds 3-4).
// Thread t owns chunk o=t&7 (32 elems) of rows 12*(t>>3)..+11. Partials
// reduced across the 8-lane octet with a DPP butterfly (VALU pipe, no LDS).
// GI chunks prefetched one chunk ahead via global_load_lds (no VGPR staging).
__global__ __launch_bounds__(512)
__attribute__((amdgpu_waves_per_eu(2, 2)))
void k_scan(const f16* __restrict__ Whh,
            const f16* __restrict__ GI,
            const float* __restrict__ h0,
            const float* __restrict__ bhh,
            const unsigned short* __restrict__ tidx,
            const int* __restrict__ lens,
            const int* __restrict__ invT,
            float* __restrict__ out) {
  const int b = blockIdx.x;
  const int tid = threadIdx.x;
  const int o = tid & 7;
  const int grp = tid >> 3;            // 0..63
  const int rbase = grp * 12;
  const bool o4 = (tid & 4) != 0, o2 = (tid & 2) != 0, o1 = (tid & 1) != 0;

  __shared__ __align__(16) f16 GIbuf[2][SCH * G3];  // 24576 B
  __shared__ float    outb[SCH * H_HID];            //  8192 B
  __shared__ float    ghs[G3];                      //  3072 B
  __shared__ uint32_t hpad[160];                    //   640 B (8 chunks, stride 20 dw)
  __shared__ unsigned short tcol[T_LEN];            //  4096 B
  __shared__ int      invcol[T_LEN];                //  8192 B

  const int L = lens[b];

  // ---- weights: rows rbase..rbase+11, elems [32o, 32o+32) -> 192 dwords ----
  uint4 wq[12][4];
#pragma unroll
  for (int i = 0; i < 12; ++i) {
    const uint4* wp = (const uint4*)(Whh + (size_t)(rbase + i) * H_HID + 32 * o);
#pragma unroll
    for (int q = 0; q < 4; ++q) wq[i][q] = wp[q];
  }
  // final rows this thread ends up holding after the butterflies
  const int rowA = rbase + o;
  const int rowB = rbase + 8 + ((tid & 4) >> 1) + ((tid & 2) >> 1);
  const float bA = bhh[rowA];
  const float bB = bhh[rowB];

  // ---- stage per-column metadata + h0 ----
  for (int i = tid; i < T_LEN; i += 512) {
    tcol[i] = tidx[b * T_LEN + i];
    invcol[i] = invT[b * T_LEN + i];
  }
  float h_reg = 0.f;
  if (tid < H_HID) {
    h_reg = h0[b * H_HID + tid];
    ((f16*)hpad)[40 * (tid >> 5) + (tid & 31)] = (f16)h_reg;
  }
  __syncthreads();   // tcol/invcol/hpad ready

  const char* GIc = (const char*)GI;
  const int wavbase = (tid >> 6) << 10;

  // issue async prefetch of chunk m into GIbuf[m&1] (16 B/lane DMA)
  auto issue_chunk = [&](int m) {
    {
      int p = tid << 4;                     // bytes [0, 8192)
      int r = p / 1536;
      int kk = m * SCH + r;
      int t = tcol[kk < L ? kk : 0] & (T_LEN - 1);
      const char* src = GIc + ((size_t)((t << 6) + b)) * 1536 + (p - r * 1536);
      char* dbase = (char*)GIbuf[m & 1] + wavbase;
      gldl16(src, dbase, (char*)GIbuf[m & 1] + p);
    }
    if (tid < 256) {                        // bytes [8192, 12288)
      int p = 8192 + (tid << 4);
      int r = p / 1536;
      int kk = m * SCH + r;
      int t = tcol[kk < L ? kk : 0] & (T_LEN - 1);
      const char* src = GIc + ((size_t)((t << 6) + b)) * 1536 + (p - r * 1536);
      char* dbase = (char*)GIbuf[m & 1] + 8192 + wavbase;
      gldl16(src, dbase, (char*)GIbuf[m & 1] + p);
    }
  };

  issue_chunk(0);

  const int nchunks = (L + SCH - 1) >> 3;
  for (int n = 0; n < nchunks; ++n) {
    const int par = n & 1;
    if (n + 1 < nchunks) issue_chunk(n + 1);   // lands during this chunk
    // flush chunk n-1 output rows (outb rows rewritten only after barrier1)
    if (n > 0) {
      int r = tid >> 6, c4 = (tid & 63) << 2;
      int kk = (n - 1) * SCH + r;
      if (kk < L) {
        int iv = invcol[kk];
        if (iv >= 0)
          *(float4*)(out + (size_t)iv * H_HID + c4) = *(const float4*)(outb + r * H_HID + c4);
      }
    }

    const int kbase = n * SCH;
    const int smax = (L - kbase < SCH) ? (L - kbase) : SCH;
    for (int s = 0; s < smax; ++s) {
      // --- matvec partials: 12 rows x own 32-elem chunk ---
      float aa[12];
#pragma unroll
      for (int i = 0; i < 12; ++i) aa[i] = 0.f;
#pragma unroll
      for (int q = 0; q < 4; ++q) {
        uint4 hv = *((const uint4*)(hpad + 20 * o) + q);
#pragma unroll
        for (int i = 0; i < 12; ++i) {
          aa[i] = fdot2f(wq[i][q].x, hv.x, aa[i]);
          aa[i] = fdot2f(wq[i][q].y, hv.y, aa[i]);
          aa[i] = fdot2f(wq[i][q].z, hv.z, aa[i]);
          aa[i] = fdot2f(wq[i][q].w, hv.w, aa[i]);
        }
      }
      // --- DPP butterfly A: rows rbase..rbase+7 -> thread holds gh[rowA] ---
      float b0 = mrg4(aa[0], aa[4], o4);
      float b1 = mrg4(aa[1], aa[5], o4);
      float b2 = mrg4(aa[2], aa[6], o4);
      float b3 = mrg4(aa[3], aa[7], o4);
      float c0 = mrg2(b0, b2, o2);
      float c1 = mrg2(b1, b3, o2);
      float ghA = mrg1(c0, c1, o1) + bA;
      // --- butterfly B: rows rbase+8..rbase+11 (dup on lane pairs) ---
      float d0 = mrg4(aa[8], aa[10], o4);
      float d1 = mrg4(aa[9], aa[11], o4);
      float e  = mrg2(d0, d1, o2);
      float ghB = e + dppf<0xB1>(e) + bB;
      ghs[rowA] = ghA;
      ghs[rowB] = ghB;   // two lanes write the same value - benign
      __syncthreads();
      // --- gates (threads 0..255) ---
      if (tid < H_HID) {
        const f16* gib = GIbuf[par] + s * G3;
        const float gi0 = (float)gib[tid];
        const float gi1 = (float)gib[H_HID + tid];
        const float gi2 = (float)gib[2 * H_HID + tid];
        const float ghr = ghs[tid];
        const float ghz = ghs[H_HID + tid];
        const float ghn = ghs[2 * H_HID + tid];
        const float rg = __builtin_amdgcn_rcpf(1.f + __expf(-(gi0 + ghr)));
        const float zg = __builtin_amdgcn_rcpf(1.f + __expf(-(gi1 + ghz)));
        const float xx = gi2 + rg * ghn;
        const float ng = 1.f - 2.f * __builtin_amdgcn_rcpf(1.f + __expf(2.f * xx));
        const float hn = (1.f - zg) * ng + zg * h_reg;
        h_reg = hn;
        ((f16*)hpad)[40 * (tid >> 5) + (tid & 31)] = (f16)hn;
        outb[s * H_HID + tid] = hn;
      }
      __syncthreads();
    }
  }
  // tail flush (last chunk)
  if (L > 0) {
    const int nc = nchunks - 1;
    int r = tid >> 6, c4 = (tid & 63) << 2;
    int kk = nc * SCH + r;
    if (kk < L) {
      int iv = invcol[kk];
      if (iv >= 0)
        *(float4*)(out + (size_t)iv * H_HID + c4) = *(const float4*)(outb + r * H_HID + c4);
    }
  }
  if (tid < H_HID)
    out[(size_t)M_ROWS * H_HID + (size_t)b * H_HID + tid] = h_reg;
}

// ---------------------------------------------------------------------------
extern "C" void kernel_launch(void* const* d_in, const int* in_sizes, int n_in,
                              void* d_out, int out_size, void* d_ws, size_t ws_size,
                              hipStream_t stream) {
  const float* x    = (const float*)d_in[0];
  const float* h0   = (const float*)d_in[1];
  const int*   mask = (const int*)d_in[2];
  const float* wih  = (const float*)d_in[3];
  const float* whh  = (const float*)d_in[4];
  const float* bih  = (const float*)d_in[5];
  const float* bhh  = (const float*)d_in[6];
  float* out = (float*)d_out;

  // workspace layout (~270.3 MB; invT reuses the X16 region after k_gemm)
  char* ws = (char*)d_ws;
  f16* X16   = (f16*)(ws + 0);                       //  67,108,864 B
  int* invT  = (int*)(ws + 0);                       //     524,288 B (after gemm)
  f16* Wih16 = (f16*)(ws + 67108864);                //     393,216 B
  f16* Whh16 = (f16*)(ws + 67502080);                //     393,216 B
  f16* GI    = (f16*)(ws + 67895296);                // 201,326,592 B
  unsigned short* tidx = (unsigned short*)(ws + 269221888);  // 262,144 B
  int* rowcnt  = (int*)(ws + 269484032);             //       8,192 B
  int* rowpref = (int*)(ws + 269492224);             //       8,192 B
  int* inv   = (int*)(ws + 269746176);               //     524,288 B
  int* lens  = (int*)(ws + 270270464);               //         256 B
  int* ntru  = (int*)(ws + 270270720);               //           4 B

  hipLaunchKernelGGL(k_zero, dim3(4096), dim3(256), 0, stream,
                     (float4*)d_out, out_size / 4);
  hipLaunchKernelGGL(k_cvt, dim3(4096), dim3(256), 0, stream,
                     (const float2*)x, (f16x2*)X16, M_ROWS * H_INP / 2);
  hipLaunchKernelGGL(k_cvt, dim3(96), dim3(256), 0, stream,
                     (const float2*)wih, (f16x2*)Wih16, G3 * H_INP / 2);
  hipLaunchKernelGGL(k_cvt, dim3(96), dim3(256), 0, stream,
                     (const float2*)whh, (f16x2*)Whh16, G3 * H_INP / 2);
  hipLaunchKernelGGL(k_prep_col, dim3(B_N), dim3(64), 0, stream,
                     mask, tidx, lens);
  hipLaunchKernelGGL(k_rowcnt, dim3(512), dim3(256), 0, stream, mask, rowcnt);
  hipLaunchKernelGGL(k_rowpref, dim3(1), dim3(512), 0, stream,
                     rowcnt, rowpref, ntru);
  hipLaunchKernelGGL(k_inv, dim3(512), dim3(256), 0, stream,
                     mask, rowpref, inv);
  hipLaunchKernelGGL(k_gemm, dim3(M_ROWS / 64, G3 / 64), dim3(256), 0, stream,
                     X16, Wih16, bih, GI);
  hipLaunchKernelGGL(k_invT, dim3(512), dim3(256), 0, stream,
                     inv, ntru, invT);
  hipLaunchKernelGGL(k_scan, dim3(B_N), dim3(512), 0, stream,
                     Whh16, GI, h0, bhh, tidx, lens, invT, out);
}